// Round 24
// baseline (182.940 us; speedup 1.0000x reference)
//
#include <hip/hip_runtime.h>
#include <math.h>

#define E_PER_B 73536
#define E_TOT   588288
#define NB 8
#define NN 384
#define NF 128
#define BLK_E 32
#define TILES_PER_BLK 4
#define K2_GRID 4596           // 4596*4*32 = 588288
#define K1_BLOCKS 1536         // 2 rows per block
#define K0B_BLOCKS 64
#define W2SCALE 1024.0f
#define W2ISCALE 0.0009765625f

typedef __attribute__((ext_vector_type(8)))  _Float16 half8;
typedef __attribute__((ext_vector_type(2)))  __fp16   fp16x2;
typedef __attribute__((ext_vector_type(16))) float    f32x16;
typedef unsigned short ushort_t;

// ---- threefry2x32, JAX partitionable scheme -> gumbel ----
__device__ __forceinline__ float gumbel_noise(unsigned l) {
  unsigned x0 = 0u;
  unsigned x1 = l;
  const unsigned ks0 = 0u, ks1 = 42u, ks2 = 0x1BD11BDAu ^ 42u;
  x0 += ks0; x1 += ks1;
#define TF_R(r) { x0 += x1; x1 = (x1 << (r)) | (x1 >> (32 - (r))); x1 ^= x0; }
  TF_R(13) TF_R(15) TF_R(26) TF_R(6)
  x0 += ks1; x1 += ks2 + 1u;
  TF_R(17) TF_R(29) TF_R(16) TF_R(24)
  x0 += ks2; x1 += ks0 + 2u;
  TF_R(13) TF_R(15) TF_R(26) TF_R(6)
  x0 += ks0; x1 += ks1 + 3u;
  TF_R(17) TF_R(29) TF_R(16) TF_R(24)
  x0 += ks1; x1 += ks2 + 4u;
  TF_R(13) TF_R(15) TF_R(26) TF_R(6)
  x0 += ks2; x1 += ks0 + 5u;
#undef TF_R
  unsigned bits = x0 ^ x1;
  float u = __uint_as_float((bits >> 9) | 0x3f800000u) - 1.0f;
  u = fmaxf(u, 1.17549435e-38f);
  float t = (float)(-log((double)u));
  return (float)(-log((double)t));
}

// ---- DPP adds on the VALU pipe (no LDS traffic) ----
template <int CTRL>
__device__ __forceinline__ float dpp_addx(float x) {
  int t = __builtin_amdgcn_update_dpp(0, __float_as_int(x), CTRL, 0xf, 0xf, true);
  return x + __int_as_float(t);
}
#define DPP_XOR1 0xB1   // quad_perm [1,0,3,2]
#define DPP_XOR2 0x4E   // quad_perm [2,3,0,1]
#define DPP_HMIR 0x141  // row_half_mirror

// --------- k01: fused prep. bid<1536: k1 (2 rows); <1600: k0b; ==1600: k0 ---
__global__ __launch_bounds__(256) void k01_prep(
    const float* __restrict__ nodes, const float* __restrict__ W1,
    const float* __restrict__ g2, const float* __restrict__ bt2,
    const float* __restrict__ W3, const float* __restrict__ b3,
    const float* __restrict__ W2,
    float* __restrict__ P, float* __restrict__ Q,
    float* __restrict__ w3g, float* __restrict__ d2c3,
    ushort_t* __restrict__ Bpk) {
  __shared__ double sbuf[256];             // 2 KB, aliased per role
  const int bid = blockIdx.x;
  const int tid = threadIdx.x;
  if (bid < K1_BLOCKS) {
    // ---- k1: P,Q for rows bid*2, bid*2+1 ----
    float* x = (float*)sbuf;
    const int half = tid >> 7, f = tid & 127;
    const int row = bid * 2 + half;
    x[half * 128 + f] = nodes[row * 128 + f];
    __syncthreads();
    const float* xr = x + half * 128;
    float p = 0.f, q = 0.f;
#pragma unroll 4
    for (int k = 0; k < 128; ++k) {
      float xk = xr[k];
      p += xk * W1[k * 128 + f];
      q += xk * W1[(128 + k) * 128 + f];
    }
    P[row * 128 + f] = p;
    Q[row * 128 + f] = q;
  } else if (bid < K1_BLOCKS + K0B_BLOCKS) {
    // ---- k0b: pre-split 1024*W2 into 2-plane fp16 (RNE) B-fragments ----
    int t = (bid - K1_BLOCKS) * 256 + tid;   // 0..16383
    int k = t >> 7, col = t & 127;
    float xs = W2[k * 128 + col] * W2SCALE;
    _Float16 hf = (_Float16)xs;              // RNE
    _Float16 mf = (_Float16)(xs - (float)hf);
    int nc = col >> 5;
    int ln = (col & 31) + ((k >> 3) & 1) * 32;
    int s  = k >> 4;
    int i  = k & 7;
    int base = ((nc * 8 + s) * 64 + ln) * 8 + i;
    Bpk[base]          = __builtin_bit_cast(ushort_t, hf);
    Bpk[16384 + base]  = __builtin_bit_cast(ushort_t, mf);
  } else {
    // ---- k0: fold LN2 affine into W3 ----
    double* red = sbuf;
    if (tid < 128) {
      w3g[tid] = g2[tid] * W3[tid];
      red[tid]       = (double)g2[tid]  * (double)W3[tid];
      red[128 + tid] = (double)bt2[tid] * (double)W3[tid];
    }
    __syncthreads();
    if (tid == 0) {
      double d2 = 0.0, c3 = 0.0;
      for (int i = 0; i < 128; ++i) { d2 += red[i]; c3 += red[128 + i]; }
      d2c3[0] = (float)d2;
      d2c3[1] = (float)(c3 + (double)b3[0]);
    }
  }
}

// ---------------- k2: fused edge MLP (MFMA fp16x2) -> logits ----------------
// R23 structure, with the MFMA-cluster pins REMOVED: no s_setprio (null for
// barrier-locked lockstep waves, m190) and no sched_barrier(0) (order-pinning
// defeats hipcc's scheduler; B-hoisting is already guarded by the opaque
// pointer). Pure scheduling change -- numerics bit-identical.
__global__ __launch_bounds__(256) void k2_edges(
    const float* __restrict__ P, const float* __restrict__ Q,
    const float* __restrict__ b1, const float* __restrict__ g1,
    const float* __restrict__ bt1, const ushort_t* __restrict__ Bpk,
    const float* __restrict__ b2, const float* __restrict__ w3g,
    const float* __restrict__ d2c3, float* __restrict__ logits) {
  __shared__ __align__(16) unsigned char sPlanes[2 * 8192];  // h,m planes (16 KB)
  __shared__ float sred[BLK_E * 97];                         // 12.4 KB
  __shared__ unsigned smeta[2][BLK_E];                       // double-buffered

  const int tid = threadIdx.x;
  const int w  = tid >> 6;           // wave 0..3 = N-strip
  const int l  = tid & 63;
  const unsigned lrow = (unsigned)(l & 31);
  const unsigned lk   = (unsigned)(l >> 5);
  const unsigned rb   = lrow * 256u;
  const unsigned esw  = lrow & 7u;
  const unsigned char* pl0 = sPlanes;
  const unsigned char* bp0 = (const unsigned char*)Bpk + (unsigned)(w * 8) * 1024u
                             + (unsigned)l * 16u;

  // epilogue constants (loop-invariant)
  const int col = w * 32 + (int)lrow;
  const float b2s = b2[col] * W2SCALE;     // pre-scaled bias (exact)
  const float w3c = w3g[col];
  const float dd2 = d2c3[0], cc3 = d2c3[1];

  half8 A0h, A0m, A1h, A1m;
  half8 B0h, B0m, B1h, B1m, B2h, B2m;

#define LOADA(S, ks) do {                                                     \
    const unsigned _co = (((unsigned)(2 * (ks)) + lk) ^ esw) << 4;            \
    A##S##h = *(const half8*)(pl0 + rb + _co);                                \
    A##S##m = *(const half8*)(pl0 + 8192 + rb + _co);                         \
  } while (0)

#define LOADB(S, ks) do {                                                     \
    B##S##h = *(const half8*)(bpt + (ks) * 1024u);                            \
    B##S##m = *(const half8*)(bpt + 32768u + (ks) * 1024u);                   \
  } while (0)

#define MFMA3(AS, BS) do {                                                    \
    acc = __builtin_amdgcn_mfma_f32_32x32x16_f16(A##AS##m, B##BS##h, acc, 0, 0, 0); \
    acc = __builtin_amdgcn_mfma_f32_32x32x16_f16(A##AS##h, B##BS##m, acc, 0, 0, 0); \
    acc = __builtin_amdgcn_mfma_f32_32x32x16_f16(A##AS##h, B##BS##h, acc, 0, 0, 0); \
  } while (0)

  for (int it = 0; it < TILES_PER_BLK; ++it) {
    const int tile = blockIdx.x * TILES_PER_BLK + it;

    // =============== phase A: h1 = LN1(relu(P[si]+Q[so]+b1)) ================
    {
      const int e = tid >> 3;        // edge 0..31
      const int q = tid & 7;         // 16-elem chunk
      int g = tile * BLK_E + e;
      int b = g / E_PER_B;
      int t0 = g - b * E_PER_B;
      int si = (int)((1.0f + sqrtf(1.0f + 8.0f * (float)t0)) * 0.5f);
      while (si * (si - 1) / 2 > t0) --si;
      while ((si + 1) * si / 2 <= t0) ++si;
      int so = t0 - si * (si - 1) / 2;
      if (q == 0) smeta[it & 1][e] = (unsigned)((b * NN + si) * (NN - 1) + so);

      const float4* P4  = (const float4*)(P + (size_t)(b * NN + si) * 128) + q * 4;
      const float4* Q4  = (const float4*)(Q + (size_t)(b * NN + so) * 128) + q * 4;
      const float4* B14 = (const float4*)b1 + q * 4;
      float av[16];
      float sum = 0.f, sq = 0.f;
#pragma unroll
      for (int k4 = 0; k4 < 4; ++k4) {
        float4 p = P4[k4], qq = Q4[k4], bb = B14[k4];
        float v0 = fmaxf(p.x + qq.x + bb.x, 0.f);
        float v1 = fmaxf(p.y + qq.y + bb.y, 0.f);
        float v2 = fmaxf(p.z + qq.z + bb.z, 0.f);
        float v3 = fmaxf(p.w + qq.w + bb.w, 0.f);
        av[4 * k4 + 0] = v0; av[4 * k4 + 1] = v1;
        av[4 * k4 + 2] = v2; av[4 * k4 + 3] = v3;
        sum += v0 + v1 + v2 + v3;
        sq += v0 * v0; sq += v1 * v1; sq += v2 * v2; sq += v3 * v3;
      }
      // two independent DPP trees (sum, sumsq) -- no serial dependency
      sum = dpp_addx<DPP_XOR1>(sum);
      sq  = dpp_addx<DPP_XOR1>(sq);
      sum = dpp_addx<DPP_XOR2>(sum);
      sq  = dpp_addx<DPP_XOR2>(sq);
      sum = dpp_addx<DPP_HMIR>(sum);
      sq  = dpp_addx<DPP_HMIR>(sq);
      float m = sum * 0.0078125f;
      float var = fmaxf(sq * 0.0078125f - m * m, 0.f);
      float rs = 1.0f / sqrtf(var + 1e-5f);

      const float4* G14  = (const float4*)g1 + q * 4;
      const float4* BT14 = (const float4*)bt1 + q * 4;
#pragma unroll
      for (int k4 = 0; k4 < 4; ++k4) {
        float4 gg = G14[k4], bt = BT14[k4];
        av[4 * k4 + 0] = (av[4 * k4 + 0] - m) * rs * gg.x + bt.x;
        av[4 * k4 + 1] = (av[4 * k4 + 1] - m) * rs * gg.y + bt.y;
        av[4 * k4 + 2] = (av[4 * k4 + 2] - m) * rs * gg.z + bt.z;
        av[4 * k4 + 3] = (av[4 * k4 + 3] - m) * rs * gg.w + bt.w;
      }
      // fp16 2-plane split via packed RTZ cvt: 3 VALU ops / element
      const unsigned esw0 = (unsigned)(e & 7);
#pragma unroll
      for (int j = 0; j < 2; ++j) {
        unsigned ph[4], pm[4];
#pragma unroll
        for (int ii = 0; ii < 4; ++ii) {
          float x0 = av[j * 8 + 2 * ii], x1 = av[j * 8 + 2 * ii + 1];
          fp16x2 hp = __builtin_amdgcn_cvt_pkrtz(x0, x1);
          float r0 = x0 - (float)hp.x;       // exact (Sterbenz)
          float r1 = x1 - (float)hp.y;
          fp16x2 mp = __builtin_amdgcn_cvt_pkrtz(r0, r1);
          ph[ii] = __builtin_bit_cast(unsigned, hp);
          pm[ii] = __builtin_bit_cast(unsigned, mp);
        }
        unsigned slot = (unsigned)(2 * q + j) ^ esw0;
        unsigned base = (unsigned)e * 256u + (slot << 4);
        *(uint4*)(sPlanes + base)        = make_uint4(ph[0], ph[1], ph[2], ph[3]);
        *(uint4*)(sPlanes + 8192 + base) = make_uint4(pm[0], pm[1], pm[2], pm[3]);
      }
    }

    // B k-steps 0,1 into slots 0,1 (issued before the barrier; opaque ptr
    // per tile prevents LICM from hoisting B out of the tile loop).
    const unsigned char* bpt = bp0;
    asm volatile("" : "+v"(bpt));
    LOADB(0, 0);
    LOADB(1, 1);

    __syncthreads();   // bar1: planes ready

    // ==== GEMM: h1[32x128] @ (1024*W2)strip[128x32], fp16x2, 3 products =====
    f32x16 acc;
#pragma unroll
    for (int i = 0; i < 16; ++i) acc[i] = 0.f;

    LOADA(0, 0);
    /* t=0 */ LOADB(2, 2); LOADA(1, 1); MFMA3(0, 0);
    /* t=1 */ LOADB(0, 3); LOADA(0, 2); MFMA3(1, 1);
    /* t=2 */ LOADB(1, 4); LOADA(1, 3); MFMA3(0, 2);
    /* t=3 */ LOADB(2, 5); LOADA(0, 4); MFMA3(1, 0);
    /* t=4 */ LOADB(0, 6); LOADA(1, 5); MFMA3(0, 1);
    /* t=5 */ LOADB(1, 7); LOADA(0, 6); MFMA3(1, 2);
    /* t=6 */ LOADA(1, 7); MFMA3(0, 0);
    /* t=7 */ MFMA3(1, 1);

    // ====== epilogue: DPP quad_perm reduce (VALU pipe, zero LDS) -> sred ====
    // rr kept at 1024x scale; pass 2 undoes it exactly (powers of 2).
    {
      const unsigned ebase = 4u * lk;
#pragma unroll
      for (int r = 0; r < 16; ++r) {
        float rr = fmaxf(acc[r] + b2s, 0.f);
        float s_ = rr, q_ = rr * rr, d_ = rr * w3c;
        s_ = dpp_addx<DPP_XOR1>(s_); q_ = dpp_addx<DPP_XOR1>(q_); d_ = dpp_addx<DPP_XOR1>(d_);
        s_ = dpp_addx<DPP_XOR2>(s_); q_ = dpp_addx<DPP_XOR2>(q_); d_ = dpp_addx<DPP_XOR2>(d_);
        if ((l & 3) == 0) {
          unsigned e = ebase + (unsigned)((r & 3) + 8 * (r >> 2));
          unsigned idx = e * 97u + (unsigned)(w * 8 + (int)(lrow >> 2)) * 3u;
          sred[idx]     = s_;
          sred[idx + 1] = q_;
          sred[idx + 2] = d_;
        }
      }
    }
    __syncthreads();   // bar2: sred ready; planes free for next tile

    // ====== pass 2 (parallel): 8 threads/edge read 12 floats each, DPP ======
    {
      const int e = tid >> 3;        // edge 0..31
      const int q = tid & 7;         // partial group 0..7 -> j = 4q..4q+3
      const float* rp = sred + e * 97 + q * 12;
      float s = rp[0] + rp[3] + rp[6] + rp[9];
      float qq = rp[1] + rp[4] + rp[7] + rp[10];
      float d = rp[2] + rp[5] + rp[8] + rp[11];
      s  = dpp_addx<DPP_XOR1>(s);  qq = dpp_addx<DPP_XOR1>(qq); d = dpp_addx<DPP_XOR1>(d);
      s  = dpp_addx<DPP_XOR2>(s);  qq = dpp_addx<DPP_XOR2>(qq); d = dpp_addx<DPP_XOR2>(d);
      s  = dpp_addx<DPP_HMIR>(s);  qq = dpp_addx<DPP_HMIR>(qq); d = dpp_addx<DPP_HMIR>(d);
      if (q == 0) {
        s *= W2ISCALE;
        qq *= W2ISCALE * W2ISCALE;
        d *= W2ISCALE;
        float m2 = s * 0.0078125f;
        float var = fmaxf(qq * 0.0078125f - m2 * m2, 0.f);
        float rs2 = 1.0f / sqrtf(var + 1e-5f);
        logits[smeta[it & 1][e]] = rs2 * d - m2 * rs2 * dd2 + cc3;
      }
    }
    // no barrier: next phase A writes planes (reads done before bar2);
    // smeta double-buffered; next sred write is after next bar1.
  }
#undef LOADA
#undef LOADB
#undef MFMA3
}

// ------- k3: zero own row + per (b,i,sample) gumbel argmax -> out=1 --------
__global__ __launch_bounds__(320) void k3_argmax(
    const float* __restrict__ logits, float* __restrict__ out) {
  int blk = blockIdx.x;
  int b = blk / NN;
  int i = blk - b * NN;
  float* row_out = out + ((size_t)(b * NN) + i) * NN;
  int t = threadIdx.x;
  if (t < 96) ((float4*)row_out)[t] = make_float4(0.f, 0.f, 0.f, 0.f);
  __syncthreads();
  if (i == 0) return;                    // row 0 stays all-zero (diag masked)
  int s = t >> 6;                        // sample 0..4 (one wave each)
  int lane = t & 63;
  const float* row = logits + (size_t)(b * NN + i) * (NN - 1);
  float best = -INFINITY;
  int bestj = 0x7fffffff;
  unsigned lbase = ((unsigned)((s * NB + b) * NN + i)) * (NN - 1);
  for (int j = lane; j < i; j += 64) {
    float v = row[j] + gumbel_noise(lbase + (unsigned)j);
    if (v > best) { best = v; bestj = j; }
  }
  for (int off = 32; off; off >>= 1) {
    float ov = __shfl_down(best, off);
    int oj = __shfl_down(bestj, off);
    if (ov > best || (ov == best && oj < bestj)) { best = ov; bestj = oj; }
  }
  if (lane == 0) row_out[bestj] = 1.0f;
}

// ---------------- launch ----------------
extern "C" void kernel_launch(void* const* d_in, const int* in_sizes, int n_in,
                              void* d_out, int out_size, void* d_ws, size_t ws_size,
                              hipStream_t stream) {
  const float* nodes = (const float*)d_in[0];
  const float* W1  = (const float*)d_in[1];
  const float* b1  = (const float*)d_in[2];
  const float* g1  = (const float*)d_in[3];
  const float* bt1 = (const float*)d_in[4];
  const float* W2  = (const float*)d_in[5];
  const float* b2  = (const float*)d_in[6];
  const float* g2  = (const float*)d_in[7];
  const float* bt2 = (const float*)d_in[8];
  const float* W3  = (const float*)d_in[9];
  const float* b3  = (const float*)d_in[10];

  float* ws     = (float*)d_ws;
  float* Pw     = ws;                 // 393216 floats
  float* Qw     = ws + 393216;        // 393216
  float* w3g    = ws + 786432;        // 128
  float* d2c3   = ws + 786560;        // 2
  float* logits = ws + 786688;        // 1176576
  ushort_t* Bpk = (ushort_t*)(ws + 1963264);  // 32768 fp16 = 64 KB

  hipLaunchKernelGGL(k01_prep, dim3(K1_BLOCKS + K0B_BLOCKS + 1), dim3(256), 0, stream,
                     nodes, W1, g2, bt2, W3, b3, W2, Pw, Qw, w3g, d2c3, Bpk);
  hipLaunchKernelGGL(k2_edges, dim3(K2_GRID), dim3(256), 0, stream,
                     Pw, Qw, b1, g1, bt1, Bpk, b2, w3g, d2c3, logits);
  hipLaunchKernelGGL(k3_argmax, dim3(NB * NN), dim3(320), 0, stream, logits, (float*)d_out);
}

// Round 25
// 171.342 us; speedup vs baseline: 1.0677x; 1.0677x over previous
//
#include <hip/hip_runtime.h>
#include <math.h>

#define E_PER_B 73536
#define E_TOT   588288
#define NB 8
#define NN 384
#define NF 128
#define BLK_E 32
#define TILES_PER_BLK 4
#define K2_GRID 4596           // 4596*4*32 = 588288
#define K1_BLOCKS 1536         // 2 rows per block
#define K0B_BLOCKS 64
#define W2SCALE 1024.0f
#define W2ISCALE 0.0009765625f

typedef __attribute__((ext_vector_type(8)))  _Float16 half8;
typedef __attribute__((ext_vector_type(2)))  __fp16   fp16x2;
typedef __attribute__((ext_vector_type(16))) float    f32x16;
typedef unsigned short ushort_t;

// ---- threefry2x32, JAX partitionable scheme -> gumbel ----
__device__ __forceinline__ float gumbel_noise(unsigned l) {
  unsigned x0 = 0u;
  unsigned x1 = l;
  const unsigned ks0 = 0u, ks1 = 42u, ks2 = 0x1BD11BDAu ^ 42u;
  x0 += ks0; x1 += ks1;
#define TF_R(r) { x0 += x1; x1 = (x1 << (r)) | (x1 >> (32 - (r))); x1 ^= x0; }
  TF_R(13) TF_R(15) TF_R(26) TF_R(6)
  x0 += ks1; x1 += ks2 + 1u;
  TF_R(17) TF_R(29) TF_R(16) TF_R(24)
  x0 += ks2; x1 += ks0 + 2u;
  TF_R(13) TF_R(15) TF_R(26) TF_R(6)
  x0 += ks0; x1 += ks1 + 3u;
  TF_R(17) TF_R(29) TF_R(16) TF_R(24)
  x0 += ks1; x1 += ks2 + 4u;
  TF_R(13) TF_R(15) TF_R(26) TF_R(6)
  x0 += ks2; x1 += ks0 + 5u;
#undef TF_R
  unsigned bits = x0 ^ x1;
  float u = __uint_as_float((bits >> 9) | 0x3f800000u) - 1.0f;
  u = fmaxf(u, 1.17549435e-38f);
  float t = (float)(-log((double)u));
  return (float)(-log((double)t));
}

// ---- DPP adds on the VALU pipe (no LDS traffic) ----
template <int CTRL>
__device__ __forceinline__ float dpp_addx(float x) {
  int t = __builtin_amdgcn_update_dpp(0, __float_as_int(x), CTRL, 0xf, 0xf, true);
  return x + __int_as_float(t);
}
#define DPP_XOR1 0xB1   // quad_perm [1,0,3,2]
#define DPP_XOR2 0x4E   // quad_perm [2,3,0,1]
#define DPP_HMIR 0x141  // row_half_mirror

// --------- k01: fused prep. bid<1536: k1 (2 rows); <1600: k0b; ==1600: k0 ---
// k0b now pre-scales W2 rows by g1 (LN1 affine fold); k0 additionally folds
// bt1@W2 into the bias: b2f = (b2 + bt1^T W2) * 1024.
__global__ __launch_bounds__(256) void k01_prep(
    const float* __restrict__ nodes, const float* __restrict__ W1,
    const float* __restrict__ g1, const float* __restrict__ bt1,
    const float* __restrict__ b2, const float* __restrict__ g2,
    const float* __restrict__ bt2, const float* __restrict__ W3,
    const float* __restrict__ b3, const float* __restrict__ W2,
    float* __restrict__ P, float* __restrict__ Q,
    float* __restrict__ w3g, float* __restrict__ d2c3,
    float* __restrict__ b2f, ushort_t* __restrict__ Bpk) {
  __shared__ double sbuf[256];             // 2 KB, aliased per role
  const int bid = blockIdx.x;
  const int tid = threadIdx.x;
  if (bid < K1_BLOCKS) {
    // ---- k1: P,Q for rows bid*2, bid*2+1 ----
    float* x = (float*)sbuf;
    const int half = tid >> 7, f = tid & 127;
    const int row = bid * 2 + half;
    x[half * 128 + f] = nodes[row * 128 + f];
    __syncthreads();
    const float* xr = x + half * 128;
    float p = 0.f, q = 0.f;
#pragma unroll 4
    for (int k = 0; k < 128; ++k) {
      float xk = xr[k];
      p += xk * W1[k * 128 + f];
      q += xk * W1[(128 + k) * 128 + f];
    }
    P[row * 128 + f] = p;
    Q[row * 128 + f] = q;
  } else if (bid < K1_BLOCKS + K0B_BLOCKS) {
    // ---- k0b: pre-split 1024*g1[k]*W2[k][col] into 2-plane fp16 (RNE) ----
    int t = (bid - K1_BLOCKS) * 256 + tid;   // 0..16383
    int k = t >> 7, col = t & 127;
    float xs = g1[k] * W2[k * 128 + col] * W2SCALE;
    _Float16 hf = (_Float16)xs;              // RNE
    _Float16 mf = (_Float16)(xs - (float)hf);
    int nc = col >> 5;
    int ln = (col & 31) + ((k >> 3) & 1) * 32;
    int s  = k >> 4;
    int i  = k & 7;
    int base = ((nc * 8 + s) * 64 + ln) * 8 + i;
    Bpk[base]          = __builtin_bit_cast(ushort_t, hf);
    Bpk[16384 + base]  = __builtin_bit_cast(ushort_t, mf);
  } else {
    // ---- k0: fold LN2 affine into W3; fold bt1@W2 into scaled bias ----
    double* red = sbuf;
    if (tid < 128) {
      w3g[tid] = g2[tid] * W3[tid];
      red[tid]       = (double)g2[tid]  * (double)W3[tid];
      red[128 + tid] = (double)bt2[tid] * (double)W3[tid];
      float c2 = 0.f;
#pragma unroll 4
      for (int k = 0; k < 128; ++k) c2 += bt1[k] * W2[k * 128 + tid];
      b2f[tid] = (b2[tid] + c2) * W2SCALE;
    }
    __syncthreads();
    if (tid == 0) {
      double d2 = 0.0, c3 = 0.0;
      for (int i = 0; i < 128; ++i) { d2 += red[i]; c3 += red[128 + i]; }
      d2c3[0] = (float)d2;
      d2c3[1] = (float)(c3 + (double)b3[0]);
    }
  }
}

// ---------------- k2: fused edge MLP (MFMA fp16x2) -> logits ----------------
// R24 structure + LN1 affine folded into W2/bias: phase A emits only
// z = fma(av, rs, -m*rs) per element (g1/bt1 loads and 32 VALU ops gone).
__global__ __launch_bounds__(256) void k2_edges(
    const float* __restrict__ P, const float* __restrict__ Q,
    const float* __restrict__ b1, const ushort_t* __restrict__ Bpk,
    const float* __restrict__ b2f, const float* __restrict__ w3g,
    const float* __restrict__ d2c3, float* __restrict__ logits) {
  __shared__ __align__(16) unsigned char sPlanes[2 * 8192];  // h,m planes (16 KB)
  __shared__ float sred[BLK_E * 97];                         // 12.4 KB
  __shared__ unsigned smeta[2][BLK_E];                       // double-buffered

  const int tid = threadIdx.x;
  const int w  = tid >> 6;           // wave 0..3 = N-strip
  const int l  = tid & 63;
  const unsigned lrow = (unsigned)(l & 31);
  const unsigned lk   = (unsigned)(l >> 5);
  const unsigned rb   = lrow * 256u;
  const unsigned esw  = lrow & 7u;
  const unsigned char* pl0 = sPlanes;
  const unsigned char* bp0 = (const unsigned char*)Bpk + (unsigned)(w * 8) * 1024u
                             + (unsigned)l * 16u;

  // epilogue constants (loop-invariant)
  const int col = w * 32 + (int)lrow;
  const float b2s = b2f[col];              // already at 1024x scale
  const float w3c = w3g[col];
  const float dd2 = d2c3[0], cc3 = d2c3[1];

  half8 A0h, A0m, A1h, A1m;
  half8 B0h, B0m, B1h, B1m, B2h, B2m;

#define LOADA(S, ks) do {                                                     \
    const unsigned _co = (((unsigned)(2 * (ks)) + lk) ^ esw) << 4;            \
    A##S##h = *(const half8*)(pl0 + rb + _co);                                \
    A##S##m = *(const half8*)(pl0 + 8192 + rb + _co);                         \
  } while (0)

#define LOADB(S, ks) do {                                                     \
    B##S##h = *(const half8*)(bpt + (ks) * 1024u);                            \
    B##S##m = *(const half8*)(bpt + 32768u + (ks) * 1024u);                   \
  } while (0)

#define MFMA3(AS, BS) do {                                                    \
    acc = __builtin_amdgcn_mfma_f32_32x32x16_f16(A##AS##m, B##BS##h, acc, 0, 0, 0); \
    acc = __builtin_amdgcn_mfma_f32_32x32x16_f16(A##AS##h, B##BS##m, acc, 0, 0, 0); \
    acc = __builtin_amdgcn_mfma_f32_32x32x16_f16(A##AS##h, B##BS##h, acc, 0, 0, 0); \
  } while (0)

  for (int it = 0; it < TILES_PER_BLK; ++it) {
    const int tile = blockIdx.x * TILES_PER_BLK + it;

    // =============== phase A: z = LN1core(relu(P[si]+Q[so]+b1)) =============
    {
      const int e = tid >> 3;        // edge 0..31
      const int q = tid & 7;         // 16-elem chunk
      int g = tile * BLK_E + e;
      int b = g / E_PER_B;
      int t0 = g - b * E_PER_B;
      int si = (int)((1.0f + sqrtf(1.0f + 8.0f * (float)t0)) * 0.5f);
      while (si * (si - 1) / 2 > t0) --si;
      while ((si + 1) * si / 2 <= t0) ++si;
      int so = t0 - si * (si - 1) / 2;
      if (q == 0) smeta[it & 1][e] = (unsigned)((b * NN + si) * (NN - 1) + so);

      const float4* P4  = (const float4*)(P + (size_t)(b * NN + si) * 128) + q * 4;
      const float4* Q4  = (const float4*)(Q + (size_t)(b * NN + so) * 128) + q * 4;
      const float4* B14 = (const float4*)b1 + q * 4;
      float av[16];
      float sum = 0.f, sq = 0.f;
#pragma unroll
      for (int k4 = 0; k4 < 4; ++k4) {
        float4 p = P4[k4], qq = Q4[k4], bb = B14[k4];
        float v0 = fmaxf(p.x + qq.x + bb.x, 0.f);
        float v1 = fmaxf(p.y + qq.y + bb.y, 0.f);
        float v2 = fmaxf(p.z + qq.z + bb.z, 0.f);
        float v3 = fmaxf(p.w + qq.w + bb.w, 0.f);
        av[4 * k4 + 0] = v0; av[4 * k4 + 1] = v1;
        av[4 * k4 + 2] = v2; av[4 * k4 + 3] = v3;
        sum += v0 + v1 + v2 + v3;
        sq += v0 * v0; sq += v1 * v1; sq += v2 * v2; sq += v3 * v3;
      }
      // two independent DPP trees (sum, sumsq) -- no serial dependency
      sum = dpp_addx<DPP_XOR1>(sum);
      sq  = dpp_addx<DPP_XOR1>(sq);
      sum = dpp_addx<DPP_XOR2>(sum);
      sq  = dpp_addx<DPP_XOR2>(sq);
      sum = dpp_addx<DPP_HMIR>(sum);
      sq  = dpp_addx<DPP_HMIR>(sq);
      float m = sum * 0.0078125f;
      float var = fmaxf(sq * 0.0078125f - m * m, 0.f);
      float rs = 1.0f / sqrtf(var + 1e-5f);
      float nrs = -m * rs;

      // fp16 2-plane split of z = av*rs + nrs (g1/bt1 folded into B/bias)
      const unsigned esw0 = (unsigned)(e & 7);
#pragma unroll
      for (int j = 0; j < 2; ++j) {
        unsigned ph[4], pm[4];
#pragma unroll
        for (int ii = 0; ii < 4; ++ii) {
          float x0 = fmaf(av[j * 8 + 2 * ii],     rs, nrs);
          float x1 = fmaf(av[j * 8 + 2 * ii + 1], rs, nrs);
          fp16x2 hp = __builtin_amdgcn_cvt_pkrtz(x0, x1);
          float r0 = x0 - (float)hp.x;       // exact (Sterbenz)
          float r1 = x1 - (float)hp.y;
          fp16x2 mp = __builtin_amdgcn_cvt_pkrtz(r0, r1);
          ph[ii] = __builtin_bit_cast(unsigned, hp);
          pm[ii] = __builtin_bit_cast(unsigned, mp);
        }
        unsigned slot = (unsigned)(2 * q + j) ^ esw0;
        unsigned base = (unsigned)e * 256u + (slot << 4);
        *(uint4*)(sPlanes + base)        = make_uint4(ph[0], ph[1], ph[2], ph[3]);
        *(uint4*)(sPlanes + 8192 + base) = make_uint4(pm[0], pm[1], pm[2], pm[3]);
      }
    }

    // B k-steps 0,1 into slots 0,1 (issued before the barrier; opaque ptr
    // per tile prevents LICM from hoisting B out of the tile loop).
    const unsigned char* bpt = bp0;
    asm volatile("" : "+v"(bpt));
    LOADB(0, 0);
    LOADB(1, 1);

    __syncthreads();   // bar1: planes ready

    // ==== GEMM: z[32x128] @ (1024*g1*W2)strip[128x32], fp16x2, 3 products ===
    f32x16 acc;
#pragma unroll
    for (int i = 0; i < 16; ++i) acc[i] = 0.f;

    LOADA(0, 0);
    /* t=0 */ LOADB(2, 2); LOADA(1, 1); MFMA3(0, 0);
    /* t=1 */ LOADB(0, 3); LOADA(0, 2); MFMA3(1, 1);
    /* t=2 */ LOADB(1, 4); LOADA(1, 3); MFMA3(0, 2);
    /* t=3 */ LOADB(2, 5); LOADA(0, 4); MFMA3(1, 0);
    /* t=4 */ LOADB(0, 6); LOADA(1, 5); MFMA3(0, 1);
    /* t=5 */ LOADB(1, 7); LOADA(0, 6); MFMA3(1, 2);
    /* t=6 */ LOADA(1, 7); MFMA3(0, 0);
    /* t=7 */ MFMA3(1, 1);

    // ====== epilogue: DPP quad_perm reduce (VALU pipe, zero LDS) -> sred ====
    // rr kept at 1024x scale; pass 2 undoes it exactly (powers of 2).
    {
      const unsigned ebase = 4u * lk;
#pragma unroll
      for (int r = 0; r < 16; ++r) {
        float rr = fmaxf(acc[r] + b2s, 0.f);
        float s_ = rr, q_ = rr * rr, d_ = rr * w3c;
        s_ = dpp_addx<DPP_XOR1>(s_); q_ = dpp_addx<DPP_XOR1>(q_); d_ = dpp_addx<DPP_XOR1>(d_);
        s_ = dpp_addx<DPP_XOR2>(s_); q_ = dpp_addx<DPP_XOR2>(q_); d_ = dpp_addx<DPP_XOR2>(d_);
        if ((l & 3) == 0) {
          unsigned e = ebase + (unsigned)((r & 3) + 8 * (r >> 2));
          unsigned idx = e * 97u + (unsigned)(w * 8 + (int)(lrow >> 2)) * 3u;
          sred[idx]     = s_;
          sred[idx + 1] = q_;
          sred[idx + 2] = d_;
        }
      }
    }
    __syncthreads();   // bar2: sred ready; planes free for next tile

    // ====== pass 2 (parallel): 8 threads/edge read 12 floats each, DPP ======
    {
      const int e = tid >> 3;        // edge 0..31
      const int q = tid & 7;         // partial group 0..7 -> j = 4q..4q+3
      const float* rp = sred + e * 97 + q * 12;
      float s = rp[0] + rp[3] + rp[6] + rp[9];
      float qq = rp[1] + rp[4] + rp[7] + rp[10];
      float d = rp[2] + rp[5] + rp[8] + rp[11];
      s  = dpp_addx<DPP_XOR1>(s);  qq = dpp_addx<DPP_XOR1>(qq); d = dpp_addx<DPP_XOR1>(d);
      s  = dpp_addx<DPP_XOR2>(s);  qq = dpp_addx<DPP_XOR2>(qq); d = dpp_addx<DPP_XOR2>(d);
      s  = dpp_addx<DPP_HMIR>(s);  qq = dpp_addx<DPP_HMIR>(qq); d = dpp_addx<DPP_HMIR>(d);
      if (q == 0) {
        s *= W2ISCALE;
        qq *= W2ISCALE * W2ISCALE;
        d *= W2ISCALE;
        float m2 = s * 0.0078125f;
        float var = fmaxf(qq * 0.0078125f - m2 * m2, 0.f);
        float rs2 = 1.0f / sqrtf(var + 1e-5f);
        logits[smeta[it & 1][e]] = rs2 * d - m2 * rs2 * dd2 + cc3;
      }
    }
    // no barrier: next phase A writes planes (reads done before bar2);
    // smeta double-buffered; next sred write is after next bar1.
  }
#undef LOADA
#undef LOADB
#undef MFMA3
}

// ------- k3: zero own row + per (b,i,sample) gumbel argmax -> out=1 --------
__global__ __launch_bounds__(320) void k3_argmax(
    const float* __restrict__ logits, float* __restrict__ out) {
  int blk = blockIdx.x;
  int b = blk / NN;
  int i = blk - b * NN;
  float* row_out = out + ((size_t)(b * NN) + i) * NN;
  int t = threadIdx.x;
  if (t < 96) ((float4*)row_out)[t] = make_float4(0.f, 0.f, 0.f, 0.f);
  __syncthreads();
  if (i == 0) return;                    // row 0 stays all-zero (diag masked)
  int s = t >> 6;                        // sample 0..4 (one wave each)
  int lane = t & 63;
  const float* row = logits + (size_t)(b * NN + i) * (NN - 1);
  float best = -INFINITY;
  int bestj = 0x7fffffff;
  unsigned lbase = ((unsigned)((s * NB + b) * NN + i)) * (NN - 1);
  for (int j = lane; j < i; j += 64) {
    float v = row[j] + gumbel_noise(lbase + (unsigned)j);
    if (v > best) { best = v; bestj = j; }
  }
  for (int off = 32; off; off >>= 1) {
    float ov = __shfl_down(best, off);
    int oj = __shfl_down(bestj, off);
    if (ov > best || (ov == best && oj < bestj)) { best = ov; bestj = oj; }
  }
  if (lane == 0) row_out[bestj] = 1.0f;
}

// ---------------- launch ----------------
extern "C" void kernel_launch(void* const* d_in, const int* in_sizes, int n_in,
                              void* d_out, int out_size, void* d_ws, size_t ws_size,
                              hipStream_t stream) {
  const float* nodes = (const float*)d_in[0];
  const float* W1  = (const float*)d_in[1];
  const float* b1  = (const float*)d_in[2];
  const float* g1  = (const float*)d_in[3];
  const float* bt1 = (const float*)d_in[4];
  const float* W2  = (const float*)d_in[5];
  const float* b2  = (const float*)d_in[6];
  const float* g2  = (const float*)d_in[7];
  const float* bt2 = (const float*)d_in[8];
  const float* W3  = (const float*)d_in[9];
  const float* b3  = (const float*)d_in[10];

  float* ws     = (float*)d_ws;
  float* Pw     = ws;                 // 393216 floats
  float* Qw     = ws + 393216;        // 393216
  float* w3g    = ws + 786432;        // 128
  float* d2c3   = ws + 786560;        // 2
  float* logits = ws + 786688;        // 1176576
  ushort_t* Bpk = (ushort_t*)(ws + 1963264);  // 32768 fp16 = 64 KB
  float* b2f    = ws + 1979648;       // 128 floats (after Bpk)

  hipLaunchKernelGGL(k01_prep, dim3(K1_BLOCKS + K0B_BLOCKS + 1), dim3(256), 0, stream,
                     nodes, W1, g1, bt1, b2, g2, bt2, W3, b3, W2,
                     Pw, Qw, w3g, d2c3, b2f, Bpk);
  hipLaunchKernelGGL(k2_edges, dim3(K2_GRID), dim3(256), 0, stream,
                     Pw, Qw, b1, Bpk, b2f, w3g, d2c3, logits);
  hipLaunchKernelGGL(k3_argmax, dim3(NB * NN), dim3(320), 0, stream, logits, (float*)d_out);
}

// Round 26
// 146.811 us; speedup vs baseline: 1.2461x; 1.1671x over previous
//
#include <hip/hip_runtime.h>
#include <math.h>

#define E_PER_B 73536
#define E_TOT   588288
#define NB 8
#define NN 384
#define NF 128
#define BLK_E 32
#define TILES_PER_BLK 4
#define K2_GRID 4596           // 4596*4*32 = 588288
#define K1_BLOCKS 768          // 4 rows per block
#define K0B_BLOCKS 64
#define W2SCALE 1024.0f
#define W2ISCALE 0.0009765625f

typedef __attribute__((ext_vector_type(8)))  _Float16 half8;
typedef __attribute__((ext_vector_type(2)))  __fp16   fp16x2;
typedef __attribute__((ext_vector_type(16))) float    f32x16;
typedef unsigned short ushort_t;

// ---- threefry2x32, JAX partitionable scheme -> gumbel (fp32 logs) ----
__device__ __forceinline__ float gumbel_noise(unsigned l) {
  unsigned x0 = 0u;
  unsigned x1 = l;
  const unsigned ks0 = 0u, ks1 = 42u, ks2 = 0x1BD11BDAu ^ 42u;
  x0 += ks0; x1 += ks1;
#define TF_R(r) { x0 += x1; x1 = (x1 << (r)) | (x1 >> (32 - (r))); x1 ^= x0; }
  TF_R(13) TF_R(15) TF_R(26) TF_R(6)
  x0 += ks1; x1 += ks2 + 1u;
  TF_R(17) TF_R(29) TF_R(16) TF_R(24)
  x0 += ks2; x1 += ks0 + 2u;
  TF_R(13) TF_R(15) TF_R(26) TF_R(6)
  x0 += ks0; x1 += ks1 + 3u;
  TF_R(17) TF_R(29) TF_R(16) TF_R(24)
  x0 += ks1; x1 += ks2 + 4u;
  TF_R(13) TF_R(15) TF_R(26) TF_R(6)
  x0 += ks2; x1 += ks0 + 5u;
#undef TF_R
  unsigned bits = x0 ^ x1;
  float u = __uint_as_float((bits >> 9) | 0x3f800000u) - 1.0f;
  u = fmaxf(u, 1.17549435e-38f);
  float t = -logf(u);
  return -logf(t);
}

// ---- DPP adds on the VALU pipe (no LDS traffic) ----
template <int CTRL>
__device__ __forceinline__ float dpp_addx(float x) {
  int t = __builtin_amdgcn_update_dpp(0, __float_as_int(x), CTRL, 0xf, 0xf, true);
  return x + __int_as_float(t);
}
#define DPP_XOR1 0xB1   // quad_perm [1,0,3,2]
#define DPP_XOR2 0x4E   // quad_perm [2,3,0,1]
#define DPP_HMIR 0x141  // row_half_mirror

// --------- k01: fused prep. bid<768: k1 (4 rows); <832: k0b; ==832: k0 ---
// k0b pre-scales W2 rows by g1 (LN1 affine fold); k0 folds bt1@W2 into the
// bias: b2f = (b2 + bt1^T W2) * 1024.
__global__ __launch_bounds__(256) void k01_prep(
    const float* __restrict__ nodes, const float* __restrict__ W1,
    const float* __restrict__ g1, const float* __restrict__ bt1,
    const float* __restrict__ b2, const float* __restrict__ g2,
    const float* __restrict__ bt2, const float* __restrict__ W3,
    const float* __restrict__ b3, const float* __restrict__ W2,
    float* __restrict__ P, float* __restrict__ Q,
    float* __restrict__ w3g, float* __restrict__ d2c3,
    float* __restrict__ b2f, ushort_t* __restrict__ Bpk) {
  __shared__ double sbuf[256];             // 2 KB, aliased per role
  const int bid = blockIdx.x;
  const int tid = threadIdx.x;
  if (bid < K1_BLOCKS) {
    // ---- k1: P,Q for rows bid*4 .. bid*4+3 (W1 traffic halved vs 2-row) ----
    float* x = (float*)sbuf;               // 512 floats = 4 rows
    const int f = tid & 127, half = tid >> 7;
    const int rowbase = bid * 4;
    x[tid]       = nodes[rowbase * 128 + tid];
    x[256 + tid] = nodes[rowbase * 128 + 256 + tid];
    __syncthreads();
    const float* xr0 = x + (half * 2) * 128;
    const float* xr1 = xr0 + 128;
    float p0 = 0.f, q0 = 0.f, p1 = 0.f, q1 = 0.f;
#pragma unroll 4
    for (int k = 0; k < 128; ++k) {
      float wp = W1[k * 128 + f];
      float wq = W1[(128 + k) * 128 + f];
      float a0 = xr0[k], a1 = xr1[k];
      p0 += a0 * wp; q0 += a0 * wq;
      p1 += a1 * wp; q1 += a1 * wq;
    }
    const int r0 = rowbase + 2 * half;
    P[r0 * 128 + f] = p0;       Q[r0 * 128 + f] = q0;
    P[(r0 + 1) * 128 + f] = p1; Q[(r0 + 1) * 128 + f] = q1;
  } else if (bid < K1_BLOCKS + K0B_BLOCKS) {
    // ---- k0b: pre-split 1024*g1[k]*W2[k][col] into 2-plane fp16 (RNE) ----
    int t = (bid - K1_BLOCKS) * 256 + tid;   // 0..16383
    int k = t >> 7, col = t & 127;
    float xs = g1[k] * W2[k * 128 + col] * W2SCALE;
    _Float16 hf = (_Float16)xs;              // RNE
    _Float16 mf = (_Float16)(xs - (float)hf);
    int nc = col >> 5;
    int ln = (col & 31) + ((k >> 3) & 1) * 32;
    int s  = k >> 4;
    int i  = k & 7;
    int base = ((nc * 8 + s) * 64 + ln) * 8 + i;
    Bpk[base]          = __builtin_bit_cast(ushort_t, hf);
    Bpk[16384 + base]  = __builtin_bit_cast(ushort_t, mf);
  } else {
    // ---- k0: fold LN2 affine into W3; fold bt1@W2 into scaled bias ----
    double* red = sbuf;
    if (tid < 128) {
      w3g[tid] = g2[tid] * W3[tid];
      red[tid]       = (double)g2[tid]  * (double)W3[tid];
      red[128 + tid] = (double)bt2[tid] * (double)W3[tid];
      float c2 = 0.f;
#pragma unroll 4
      for (int k = 0; k < 128; ++k) c2 += bt1[k] * W2[k * 128 + tid];
      b2f[tid] = (b2[tid] + c2) * W2SCALE;
    }
    __syncthreads();
    if (tid == 0) {
      double d2 = 0.0, c3 = 0.0;
      for (int i = 0; i < 128; ++i) { d2 += red[i]; c3 += red[128 + i]; }
      d2c3[0] = (float)d2;
      d2c3[1] = (float)(c3 + (double)b3[0]);
    }
  }
}

// ---------------- k2: fused edge MLP (MFMA fp16x2) -> logits ----------------
// R25 structure unchanged (validated 128 us, absmax 0).
__global__ __launch_bounds__(256) void k2_edges(
    const float* __restrict__ P, const float* __restrict__ Q,
    const float* __restrict__ b1, const ushort_t* __restrict__ Bpk,
    const float* __restrict__ b2f, const float* __restrict__ w3g,
    const float* __restrict__ d2c3, float* __restrict__ logits) {
  __shared__ __align__(16) unsigned char sPlanes[2 * 8192];  // h,m planes (16 KB)
  __shared__ float sred[BLK_E * 97];                         // 12.4 KB
  __shared__ unsigned smeta[2][BLK_E];                       // double-buffered

  const int tid = threadIdx.x;
  const int w  = tid >> 6;           // wave 0..3 = N-strip
  const int l  = tid & 63;
  const unsigned lrow = (unsigned)(l & 31);
  const unsigned lk   = (unsigned)(l >> 5);
  const unsigned rb   = lrow * 256u;
  const unsigned esw  = lrow & 7u;
  const unsigned char* pl0 = sPlanes;
  const unsigned char* bp0 = (const unsigned char*)Bpk + (unsigned)(w * 8) * 1024u
                             + (unsigned)l * 16u;

  // epilogue constants (loop-invariant)
  const int col = w * 32 + (int)lrow;
  const float b2s = b2f[col];              // already at 1024x scale
  const float w3c = w3g[col];
  const float dd2 = d2c3[0], cc3 = d2c3[1];

  half8 A0h, A0m, A1h, A1m;
  half8 B0h, B0m, B1h, B1m, B2h, B2m;

#define LOADA(S, ks) do {                                                     \
    const unsigned _co = (((unsigned)(2 * (ks)) + lk) ^ esw) << 4;            \
    A##S##h = *(const half8*)(pl0 + rb + _co);                                \
    A##S##m = *(const half8*)(pl0 + 8192 + rb + _co);                         \
  } while (0)

#define LOADB(S, ks) do {                                                     \
    B##S##h = *(const half8*)(bpt + (ks) * 1024u);                            \
    B##S##m = *(const half8*)(bpt + 32768u + (ks) * 1024u);                   \
  } while (0)

#define MFMA3(AS, BS) do {                                                    \
    acc = __builtin_amdgcn_mfma_f32_32x32x16_f16(A##AS##m, B##BS##h, acc, 0, 0, 0); \
    acc = __builtin_amdgcn_mfma_f32_32x32x16_f16(A##AS##h, B##BS##m, acc, 0, 0, 0); \
    acc = __builtin_amdgcn_mfma_f32_32x32x16_f16(A##AS##h, B##BS##h, acc, 0, 0, 0); \
  } while (0)

  for (int it = 0; it < TILES_PER_BLK; ++it) {
    const int tile = blockIdx.x * TILES_PER_BLK + it;

    // =============== phase A: z = LN1core(relu(P[si]+Q[so]+b1)) =============
    {
      const int e = tid >> 3;        // edge 0..31
      const int q = tid & 7;         // 16-elem chunk
      int g = tile * BLK_E + e;
      int b = g / E_PER_B;
      int t0 = g - b * E_PER_B;
      int si = (int)((1.0f + sqrtf(1.0f + 8.0f * (float)t0)) * 0.5f);
      while (si * (si - 1) / 2 > t0) --si;
      while ((si + 1) * si / 2 <= t0) ++si;
      int so = t0 - si * (si - 1) / 2;
      if (q == 0) smeta[it & 1][e] = (unsigned)((b * NN + si) * (NN - 1) + so);

      const float4* P4  = (const float4*)(P + (size_t)(b * NN + si) * 128) + q * 4;
      const float4* Q4  = (const float4*)(Q + (size_t)(b * NN + so) * 128) + q * 4;
      const float4* B14 = (const float4*)b1 + q * 4;
      float av[16];
      float sum = 0.f, sq = 0.f;
#pragma unroll
      for (int k4 = 0; k4 < 4; ++k4) {
        float4 p = P4[k4], qq = Q4[k4], bb = B14[k4];
        float v0 = fmaxf(p.x + qq.x + bb.x, 0.f);
        float v1 = fmaxf(p.y + qq.y + bb.y, 0.f);
        float v2 = fmaxf(p.z + qq.z + bb.z, 0.f);
        float v3 = fmaxf(p.w + qq.w + bb.w, 0.f);
        av[4 * k4 + 0] = v0; av[4 * k4 + 1] = v1;
        av[4 * k4 + 2] = v2; av[4 * k4 + 3] = v3;
        sum += v0 + v1 + v2 + v3;
        sq += v0 * v0; sq += v1 * v1; sq += v2 * v2; sq += v3 * v3;
      }
      // two independent DPP trees (sum, sumsq) -- no serial dependency
      sum = dpp_addx<DPP_XOR1>(sum);
      sq  = dpp_addx<DPP_XOR1>(sq);
      sum = dpp_addx<DPP_XOR2>(sum);
      sq  = dpp_addx<DPP_XOR2>(sq);
      sum = dpp_addx<DPP_HMIR>(sum);
      sq  = dpp_addx<DPP_HMIR>(sq);
      float m = sum * 0.0078125f;
      float var = fmaxf(sq * 0.0078125f - m * m, 0.f);
      float rs = 1.0f / sqrtf(var + 1e-5f);
      float nrs = -m * rs;

      // fp16 2-plane split of z = av*rs + nrs (g1/bt1 folded into B/bias)
      const unsigned esw0 = (unsigned)(e & 7);
#pragma unroll
      for (int j = 0; j < 2; ++j) {
        unsigned ph[4], pm[4];
#pragma unroll
        for (int ii = 0; ii < 4; ++ii) {
          float x0 = fmaf(av[j * 8 + 2 * ii],     rs, nrs);
          float x1 = fmaf(av[j * 8 + 2 * ii + 1], rs, nrs);
          fp16x2 hp = __builtin_amdgcn_cvt_pkrtz(x0, x1);
          float r0 = x0 - (float)hp.x;       // exact (Sterbenz)
          float r1 = x1 - (float)hp.y;
          fp16x2 mp = __builtin_amdgcn_cvt_pkrtz(r0, r1);
          ph[ii] = __builtin_bit_cast(unsigned, hp);
          pm[ii] = __builtin_bit_cast(unsigned, mp);
        }
        unsigned slot = (unsigned)(2 * q + j) ^ esw0;
        unsigned base = (unsigned)e * 256u + (slot << 4);
        *(uint4*)(sPlanes + base)        = make_uint4(ph[0], ph[1], ph[2], ph[3]);
        *(uint4*)(sPlanes + 8192 + base) = make_uint4(pm[0], pm[1], pm[2], pm[3]);
      }
    }

    // B k-steps 0,1 into slots 0,1 (issued before the barrier; opaque ptr
    // per tile prevents LICM from hoisting B out of the tile loop).
    const unsigned char* bpt = bp0;
    asm volatile("" : "+v"(bpt));
    LOADB(0, 0);
    LOADB(1, 1);

    __syncthreads();   // bar1: planes ready

    // ==== GEMM: z[32x128] @ (1024*g1*W2)strip[128x32], fp16x2, 3 products ===
    f32x16 acc;
#pragma unroll
    for (int i = 0; i < 16; ++i) acc[i] = 0.f;

    LOADA(0, 0);
    /* t=0 */ LOADB(2, 2); LOADA(1, 1); MFMA3(0, 0);
    /* t=1 */ LOADB(0, 3); LOADA(0, 2); MFMA3(1, 1);
    /* t=2 */ LOADB(1, 4); LOADA(1, 3); MFMA3(0, 2);
    /* t=3 */ LOADB(2, 5); LOADA(0, 4); MFMA3(1, 0);
    /* t=4 */ LOADB(0, 6); LOADA(1, 5); MFMA3(0, 1);
    /* t=5 */ LOADB(1, 7); LOADA(0, 6); MFMA3(1, 2);
    /* t=6 */ LOADA(1, 7); MFMA3(0, 0);
    /* t=7 */ MFMA3(1, 1);

    // ====== epilogue: DPP quad_perm reduce (VALU pipe, zero LDS) -> sred ====
    // rr kept at 1024x scale; pass 2 undoes it exactly (powers of 2).
    {
      const unsigned ebase = 4u * lk;
#pragma unroll
      for (int r = 0; r < 16; ++r) {
        float rr = fmaxf(acc[r] + b2s, 0.f);
        float s_ = rr, q_ = rr * rr, d_ = rr * w3c;
        s_ = dpp_addx<DPP_XOR1>(s_); q_ = dpp_addx<DPP_XOR1>(q_); d_ = dpp_addx<DPP_XOR1>(d_);
        s_ = dpp_addx<DPP_XOR2>(s_); q_ = dpp_addx<DPP_XOR2>(q_); d_ = dpp_addx<DPP_XOR2>(d_);
        if ((l & 3) == 0) {
          unsigned e = ebase + (unsigned)((r & 3) + 8 * (r >> 2));
          unsigned idx = e * 97u + (unsigned)(w * 8 + (int)(lrow >> 2)) * 3u;
          sred[idx]     = s_;
          sred[idx + 1] = q_;
          sred[idx + 2] = d_;
        }
      }
    }
    __syncthreads();   // bar2: sred ready; planes free for next tile

    // ====== pass 2 (parallel): 8 threads/edge read 12 floats each, DPP ======
    {
      const int e = tid >> 3;        // edge 0..31
      const int q = tid & 7;         // partial group 0..7 -> j = 4q..4q+3
      const float* rp = sred + e * 97 + q * 12;
      float s = rp[0] + rp[3] + rp[6] + rp[9];
      float qq = rp[1] + rp[4] + rp[7] + rp[10];
      float d = rp[2] + rp[5] + rp[8] + rp[11];
      s  = dpp_addx<DPP_XOR1>(s);  qq = dpp_addx<DPP_XOR1>(qq); d = dpp_addx<DPP_XOR1>(d);
      s  = dpp_addx<DPP_XOR2>(s);  qq = dpp_addx<DPP_XOR2>(qq); d = dpp_addx<DPP_XOR2>(d);
      s  = dpp_addx<DPP_HMIR>(s);  qq = dpp_addx<DPP_HMIR>(qq); d = dpp_addx<DPP_HMIR>(d);
      if (q == 0) {
        s *= W2ISCALE;
        qq *= W2ISCALE * W2ISCALE;
        d *= W2ISCALE;
        float m2 = s * 0.0078125f;
        float var = fmaxf(qq * 0.0078125f - m2 * m2, 0.f);
        float rs2 = 1.0f / sqrtf(var + 1e-5f);
        logits[smeta[it & 1][e]] = rs2 * d - m2 * rs2 * dd2 + cc3;
      }
    }
    // no barrier: next phase A writes planes (reads done before bar2);
    // smeta double-buffered; next sred write is after next bar1.
  }
#undef LOADA
#undef LOADB
#undef MFMA3
}

// ------- k3: zero own row + per (b,i,sample) gumbel argmax -> out=1 --------
__global__ __launch_bounds__(320) void k3_argmax(
    const float* __restrict__ logits, float* __restrict__ out) {
  int blk = blockIdx.x;
  int b = blk / NN;
  int i = blk - b * NN;
  float* row_out = out + ((size_t)(b * NN) + i) * NN;
  int t = threadIdx.x;
  if (t < 96) ((float4*)row_out)[t] = make_float4(0.f, 0.f, 0.f, 0.f);
  __syncthreads();
  if (i == 0) return;                    // row 0 stays all-zero (diag masked)
  int s = t >> 6;                        // sample 0..4 (one wave each)
  int lane = t & 63;
  const float* row = logits + (size_t)(b * NN + i) * (NN - 1);
  float best = -INFINITY;
  int bestj = 0x7fffffff;
  unsigned lbase = ((unsigned)((s * NB + b) * NN + i)) * (NN - 1);
  for (int j = lane; j < i; j += 64) {
    float v = row[j] + gumbel_noise(lbase + (unsigned)j);
    if (v > best) { best = v; bestj = j; }
  }
  for (int off = 32; off; off >>= 1) {
    float ov = __shfl_down(best, off);
    int oj = __shfl_down(bestj, off);
    if (ov > best || (ov == best && oj < bestj)) { best = ov; bestj = oj; }
  }
  if (lane == 0) row_out[bestj] = 1.0f;
}

// ---------------- launch ----------------
extern "C" void kernel_launch(void* const* d_in, const int* in_sizes, int n_in,
                              void* d_out, int out_size, void* d_ws, size_t ws_size,
                              hipStream_t stream) {
  const float* nodes = (const float*)d_in[0];
  const float* W1  = (const float*)d_in[1];
  const float* b1  = (const float*)d_in[2];
  const float* g1  = (const float*)d_in[3];
  const float* bt1 = (const float*)d_in[4];
  const float* W2  = (const float*)d_in[5];
  const float* b2  = (const float*)d_in[6];
  const float* g2  = (const float*)d_in[7];
  const float* bt2 = (const float*)d_in[8];
  const float* W3  = (const float*)d_in[9];
  const float* b3  = (const float*)d_in[10];

  float* ws     = (float*)d_ws;
  float* Pw     = ws;                 // 393216 floats
  float* Qw     = ws + 393216;        // 393216
  float* w3g    = ws + 786432;        // 128
  float* d2c3   = ws + 786560;        // 2
  float* logits = ws + 786688;        // 1176576
  ushort_t* Bpk = (ushort_t*)(ws + 1963264);  // 32768 fp16 = 64 KB
  float* b2f    = ws + 1979648;       // 128 floats (after Bpk)

  hipLaunchKernelGGL(k01_prep, dim3(K1_BLOCKS + K0B_BLOCKS + 1), dim3(256), 0, stream,
                     nodes, W1, g1, bt1, b2, g2, bt2, W3, b3, W2,
                     Pw, Qw, w3g, d2c3, b2f, Bpk);
  hipLaunchKernelGGL(k2_edges, dim3(K2_GRID), dim3(256), 0, stream,
                     Pw, Qw, b1, Bpk, b2f, w3g, d2c3, logits);
  hipLaunchKernelGGL(k3_argmax, dim3(NB * NN), dim3(320), 0, stream, logits, (float*)d_out);
}